// Round 3
// baseline (1744.880 us; speedup 1.0000x reference)
//
#include <hip/hip_runtime.h>
#include <hip/hip_bf16.h>

// EntityTable: B=16,T=2048,D=1024,N_E=8,D_E=64
// Phase A (parallel): hp = h@Wi^T + bi ; logits = h@ek^T/32 ; w = softmax(logits)
//                     P  = W_ih @ hp   (entity-independent input-gate projection)
// Phase B (sequential scan over T): per cell (b,n):
//   gx_k = w*P_k + b_ih_k ; gh_k = W_hh[k]·s + b_hh_k
//   r=sig(gx0+gh0) z=sig(gx1+gh1) n=tanh(gx2 + r*gh2) ; s' = (1-z)n + z s
//
// Round-3 scan: ONE WAVE per cell. Lane j owns gate rows {j, 64+j, 128+j}
// (weights in 192 VGPRs), does all 3 dots itself, activation in-lane, and
// the only cross-lane exchange is one same-wave LDS write->read hop for the
// 64-float state. No barriers anywhere in the loop; no redundant DS traffic.

constexpr int B_  = 16;
constexpr int T_  = 2048;
constexpr int D_  = 1024;
constexpr int NE  = 8;
constexpr int DE  = 64;
constexpr int G3  = 192;            // 3*DE
constexpr int ROWS = B_ * T_;       // 32768
constexpr int OUT1OFF = ROWS * NE * DE;  // 16777216

// ---------------- Kernel T: transpose Wi -> WT4 ----------------
// WT4[(dq*64 + o)*4 + i] = Wi[o*1024 + dq*4 + i]
__global__ __launch_bounds__(256) void wt_kernel(
    const float* __restrict__ Wi, float* __restrict__ WT4)
{
    const int o  = blockIdx.x;     // 64 blocks
    const int dq = threadIdx.x;    // 256 threads
    const float4 v = *(const float4*)&Wi[o * D_ + dq * 4];
    *(float4*)&WT4[(dq * 64 + o) * 4] = v;
}

// ---------------- Kernel A: projection + routing + P ----------------
constexpr int RPB = 32;   // rows per block
constexpr int CH  = 128;  // K-chunk

__global__ __launch_bounds__(256) void proj_kernel(
    const float* __restrict__ h,   const float* __restrict__ ek,
    const float* __restrict__ WT4, const float* __restrict__ bi,
    const float* __restrict__ Wih,
    float* __restrict__ Pout, float* __restrict__ wout)
{
    __shared__ float hch[RPB][CH];   // 16 KB
    __shared__ float hp[RPB][DE];    // 8 KB
    __shared__ float lg[RPB][NE];    // 1 KB

    const int tid = threadIdx.x;
    const int brow = blockIdx.x * RPB;
    const int w = tid >> 6;          // wave 0..3
    const int o = tid & 63;          // lane = output index for hp
    const int n  = o & 7;            // entity for logit partial
    const int sl = o >> 3;           // K-slice for logit partial

    float acc[8], accl[8];
#pragma unroll
    for (int r = 0; r < 8; ++r) { acc[r] = 0.f; accl[r] = 0.f; }

    for (int kc = 0; kc < D_; kc += CH) {
        __syncthreads();
#pragma unroll
        for (int i = 0; i < 4; ++i) {
            int idx = tid + i * 256;
            int lr = idx >> 5;
            int c4 = (idx & 31) * 4;
            *(float4*)&hch[lr][c4] =
                *(const float4*)&h[(size_t)(brow + lr) * D_ + kc + c4];
        }
        __syncthreads();

        for (int d4 = 0; d4 < CH / 4; ++d4) {
            const float4 wt = *(const float4*)&WT4[((kc >> 2) + d4) * 256 + (o << 2)];
#pragma unroll
            for (int r = 0; r < 8; ++r) {
                const float4 h4 = *(const float4*)&hch[w * 8 + r][d4 * 4];
                acc[r] = fmaf(wt.x, h4.x,
                         fmaf(wt.y, h4.y,
                         fmaf(wt.z, h4.z,
                         fmaf(wt.w, h4.w, acc[r]))));
            }
        }
#pragma unroll
        for (int i4 = 0; i4 < 4; ++i4) {
            const int dl = sl * 16 + i4 * 4;
            const float4 e4 = *(const float4*)&ek[n * D_ + kc + dl];
#pragma unroll
            for (int r = 0; r < 8; ++r) {
                const float4 h4 = *(const float4*)&hch[w * 8 + r][dl];
                accl[r] = fmaf(e4.x, h4.x,
                          fmaf(e4.y, h4.y,
                          fmaf(e4.z, h4.z,
                          fmaf(e4.w, h4.w, accl[r]))));
            }
        }
    }

    const float biv = bi[o];
#pragma unroll
    for (int r = 0; r < 8; ++r) hp[w * 8 + r][o] = acc[r] + biv;

#pragma unroll
    for (int r = 0; r < 8; ++r) {
        accl[r] += __shfl_xor(accl[r], 8);
        accl[r] += __shfl_xor(accl[r], 16);
        accl[r] += __shfl_xor(accl[r], 32);
    }
    if (sl == 0) {
#pragma unroll
        for (int r = 0; r < 8; ++r) lg[w * 8 + r][n] = accl[r] * 0.03125f;
    }
    __syncthreads();

    if (tid < RPB) {
        const int lr = tid;
        float v[NE];
        float m = -1e30f;
#pragma unroll
        for (int e = 0; e < NE; ++e) { v[e] = lg[lr][e]; m = fmaxf(m, v[e]); }
        float s = 0.f;
#pragma unroll
        for (int e = 0; e < NE; ++e) { v[e] = __expf(v[e] - m); s += v[e]; }
        const float inv = 1.f / s;
#pragma unroll
        for (int e = 0; e < NE; ++e)
            wout[(size_t)(brow + lr) * NE + e] = v[e] * inv;
    }

    if (tid < G3) {
        const int k = tid;
        for (int lr0 = 0; lr0 < RPB; lr0 += 8) {
            float pacc[8];
#pragma unroll
            for (int r = 0; r < 8; ++r) pacc[r] = 0.f;
            for (int d4 = 0; d4 < DE / 4; ++d4) {
                const float4 wv = *(const float4*)&Wih[k * DE + d4 * 4];
#pragma unroll
                for (int r = 0; r < 8; ++r) {
                    const float4 h4 = *(const float4*)&hp[lr0 + r][d4 * 4];
                    pacc[r] = fmaf(wv.x, h4.x,
                              fmaf(wv.y, h4.y,
                              fmaf(wv.z, h4.z,
                              fmaf(wv.w, h4.w, pacc[r]))));
                }
            }
#pragma unroll
            for (int r = 0; r < 8; ++r)
                Pout[(size_t)(brow + lr0 + r) * G3 + k] = pacc[r];
        }
    }
}

// ---------------- Kernel B: one-wave-per-cell GRU scan ----------------
// 128 blocks x 64 threads. Lane j: gate rows {j, 64+j, 128+j} in registers.
__global__ __launch_bounds__(64, 1) void scan_kernel(
    const float* __restrict__ P,   const float* __restrict__ route,
    const float* __restrict__ Whh, const float* __restrict__ bih,
    const float* __restrict__ bhh, const float* __restrict__ e0,
    float* __restrict__ out, int write1)
{
    __shared__ __align__(16) float s_l[DE];

    const int cell = blockIdx.x;
    const int b = cell >> 3;
    const int n = cell & 7;
    const int j = threadIdx.x;          // 0..63

    // W_hh rows k=j (r-gate), 64+j (z-gate), 128+j (n-gate) in registers
    float wr[DE], wz[DE], wn_[DE];
#pragma unroll
    for (int q = 0; q < 16; ++q) {
        *(float4*)&wr[q * 4]  = *(const float4*)&Whh[(size_t)(j)       * DE + q * 4];
        *(float4*)&wz[q * 4]  = *(const float4*)&Whh[(size_t)(64 + j)  * DE + q * 4];
        *(float4*)&wn_[q * 4] = *(const float4*)&Whh[(size_t)(128 + j) * DE + q * 4];
    }
    const float bir = bih[j], biz = bih[64 + j], bin = bih[128 + j];
    const float bhr = bhh[j], bhz = bhh[64 + j], bhn = bhh[128 + j];

    const size_t row0 = (size_t)b * T_;
    float s_reg = e0[n * DE + j];
    s_l[j] = s_reg;                      // same-wave; compiler orders via lgkmcnt

    const float* Pr   = P + row0 * G3;
    const float* wrow = route + row0 * NE + n;

    float prc[4], pzc[4], pnc[4], wc[4];
#pragma unroll
    for (int i = 0; i < 4; ++i) {
        prc[i] = Pr[(size_t)i * G3 + j];
        pzc[i] = Pr[(size_t)i * G3 + 64 + j];
        pnc[i] = Pr[(size_t)i * G3 + 128 + j];
        wc[i]  = wrow[i * NE];
    }

    for (int t0 = 0; t0 < T_; t0 += 4) {
        const int t4 = (t0 + 4 < T_) ? (t0 + 4) : t0;   // last group reloads (harmless)
        float prn[4], pzn[4], pnn[4], wn4[4];
#pragma unroll
        for (int i = 0; i < 4; ++i) {
            prn[i] = Pr[(size_t)(t4 + i) * G3 + j];
            pzn[i] = Pr[(size_t)(t4 + i) * G3 + 64 + j];
            pnn[i] = Pr[(size_t)(t4 + i) * G3 + 128 + j];
            wn4[i] = wrow[(t4 + i) * NE];
        }

#pragma unroll
        for (int i = 0; i < 4; ++i) {
            const int t = t0 + i;
            const float gxr = fmaf(wc[i], prc[i], bir);
            const float gxz = fmaf(wc[i], pzc[i], biz);
            const float gxn = fmaf(wc[i], pnc[i], bin);

            float ra[4] = {0.f, 0.f, 0.f, 0.f};
            float za[4] = {0.f, 0.f, 0.f, 0.f};
            float na[4] = {0.f, 0.f, 0.f, 0.f};
#pragma unroll
            for (int q = 0; q < 16; ++q) {
                const float4 s4 = *(const float4*)&s_l[q * 4];  // broadcast read
                const int a = q & 3;
                ra[a] = fmaf(wr[q*4+0], s4.x, fmaf(wr[q*4+1], s4.y,
                        fmaf(wr[q*4+2], s4.z, fmaf(wr[q*4+3], s4.w, ra[a]))));
                za[a] = fmaf(wz[q*4+0], s4.x, fmaf(wz[q*4+1], s4.y,
                        fmaf(wz[q*4+2], s4.z, fmaf(wz[q*4+3], s4.w, za[a]))));
                na[a] = fmaf(wn_[q*4+0], s4.x, fmaf(wn_[q*4+1], s4.y,
                        fmaf(wn_[q*4+2], s4.z, fmaf(wn_[q*4+3], s4.w, na[a]))));
            }
            const float ghr = ((ra[0] + ra[1]) + (ra[2] + ra[3])) + bhr;
            const float ghz = ((za[0] + za[1]) + (za[2] + za[3])) + bhz;
            const float ghn = ((na[0] + na[1]) + (na[2] + na[3])) + bhn;

            const float rr = 1.f / (1.f + __expf(-(gxr + ghr)));
            const float zz = 1.f / (1.f + __expf(-(gxz + ghz)));
            const float x  = fmaf(rr, ghn, gxn);
            const float nn = 1.f - 2.f / (__expf(2.f * x) + 1.f);   // tanh(x)
            const float snew = fmaf(zz, s_reg - nn, nn);
            s_reg = snew;
            s_l[j] = snew;               // the single cross-lane hop

            const size_t o0 = (row0 + t) * (size_t)(NE * DE) + n * DE + j;
            out[o0] = snew;
            if (write1) out[OUT1OFF + o0] = snew;
        }

#pragma unroll
        for (int i = 0; i < 4; ++i) {
            prc[i] = prn[i]; pzc[i] = pzn[i]; pnc[i] = pnn[i]; wc[i] = wn4[i];
        }
    }
}

extern "C" void kernel_launch(void* const* d_in, const int* in_sizes, int n_in,
                              void* d_out, int out_size, void* d_ws, size_t ws_size,
                              hipStream_t stream) {
    const float* h_seq = (const float*)d_in[0];
    const float* ek    = (const float*)d_in[1];
    const float* Wi    = (const float*)d_in[2];
    const float* bi    = (const float*)d_in[3];
    const float* Wih   = (const float*)d_in[4];
    const float* Whh   = (const float*)d_in[5];
    const float* bih   = (const float*)d_in[6];
    const float* bhh   = (const float*)d_in[7];
    const float* e0    = (const float*)d_in[8];
    float* out = (float*)d_out;

    const size_t need = (size_t)ROWS * (G3 + NE) * sizeof(float)
                      + (size_t)DE * D_ * sizeof(float);  // ~26.5 MB
    float* wbuf;
    float* Pbuf;
    float* WT4;
    int write1;
    if (ws_size >= need) {
        wbuf = (float*)d_ws;
        Pbuf = wbuf + (size_t)ROWS * NE;
        WT4  = Pbuf + (size_t)ROWS * G3;
        write1 = 1;
    } else {
        wbuf = out + OUT1OFF;
        Pbuf = wbuf + (size_t)ROWS * NE;
        WT4  = Pbuf + (size_t)ROWS * G3;
        write1 = 0;
    }

    wt_kernel<<<DE, 256, 0, stream>>>(Wi, WT4);
    proj_kernel<<<ROWS / RPB, 256, 0, stream>>>(h_seq, ek, WT4, bi, Wih, Pbuf, wbuf);
    scan_kernel<<<B_ * NE, 64, 0, stream>>>(Pbuf, wbuf, Whh, bih, bhh, e0, out, write1);

    if (!write1) {
        hipMemcpyAsync(out + OUT1OFF, out, (size_t)OUT1OFF * sizeof(float),
                       hipMemcpyDeviceToDevice, stream);
    }
}

// Round 4
// 1128.257 us; speedup vs baseline: 1.5465x; 1.5465x over previous
//
#include <hip/hip_runtime.h>
#include <hip/hip_bf16.h>

// EntityTable: B=16,T=2048,D=1024,N_E=8,D_E=64
// Phase A (parallel): hp = h@Wi^T + bi ; logits = h@ek^T/32 ; w = softmax(logits)
//                     P  = W_ih @ hp   (entity-independent input-gate projection)
// Phase B (sequential scan over T): per cell (b,n):
//   gx_k = w*P_k + b_ih_k ; gh_k = W_hh[k]·s + b_hh_k
//   r=sig(gx0+gh0) z=sig(gx1+gh1) n=tanh(gx2 + r*gh2) ; s' = (1-z)n + z s
//
// Round-4 scan: one wave per cell; weights as f32x2 in arch VGPRs, dot via
// v_pk_fma_f32 inline asm (halves issue count; "v" constraints pin arch regs).
// One LDS broadcast hop per step, zero barriers, out1 via separate copy kernel.

constexpr int B_  = 16;
constexpr int T_  = 2048;
constexpr int D_  = 1024;
constexpr int NE  = 8;
constexpr int DE  = 64;
constexpr int G3  = 192;            // 3*DE
constexpr int ROWS = B_ * T_;       // 32768
constexpr int OUT1OFF = ROWS * NE * DE;  // 16777216

typedef __attribute__((ext_vector_type(2))) float f32x2;
typedef __attribute__((ext_vector_type(4))) float f32x4;

__device__ __forceinline__ void pkacc(f32x2& acc, f32x2 w, f32x2 s) {
    asm("v_pk_fma_f32 %0, %1, %2, %0" : "+v"(acc) : "v"(w), "v"(s));
}

// ---------------- Kernel T: transpose Wi -> WT4 ----------------
__global__ __launch_bounds__(256) void wt_kernel(
    const float* __restrict__ Wi, float* __restrict__ WT4)
{
    const int o  = blockIdx.x;     // 64 blocks
    const int dq = threadIdx.x;    // 256 threads
    const float4 v = *(const float4*)&Wi[o * D_ + dq * 4];
    *(float4*)&WT4[(dq * 64 + o) * 4] = v;
}

// ---------------- Kernel A: projection + routing + P ----------------
constexpr int RPB = 32;   // rows per block
constexpr int CH  = 128;  // K-chunk

__global__ __launch_bounds__(256) void proj_kernel(
    const float* __restrict__ h,   const float* __restrict__ ek,
    const float* __restrict__ WT4, const float* __restrict__ bi,
    const float* __restrict__ Wih,
    float* __restrict__ Pout, float* __restrict__ wout)
{
    __shared__ float hch[RPB][CH];   // 16 KB
    __shared__ float hp[RPB][DE];    // 8 KB
    __shared__ float lg[RPB][NE];    // 1 KB

    const int tid = threadIdx.x;
    const int brow = blockIdx.x * RPB;
    const int w = tid >> 6;          // wave 0..3
    const int o = tid & 63;          // lane = output index for hp
    const int n  = o & 7;            // entity for logit partial
    const int sl = o >> 3;           // K-slice for logit partial

    float acc[8], accl[8];
#pragma unroll
    for (int r = 0; r < 8; ++r) { acc[r] = 0.f; accl[r] = 0.f; }

    for (int kc = 0; kc < D_; kc += CH) {
        __syncthreads();
#pragma unroll
        for (int i = 0; i < 4; ++i) {
            int idx = tid + i * 256;
            int lr = idx >> 5;
            int c4 = (idx & 31) * 4;
            *(float4*)&hch[lr][c4] =
                *(const float4*)&h[(size_t)(brow + lr) * D_ + kc + c4];
        }
        __syncthreads();

        for (int d4 = 0; d4 < CH / 4; ++d4) {
            const float4 wt = *(const float4*)&WT4[((kc >> 2) + d4) * 256 + (o << 2)];
#pragma unroll
            for (int r = 0; r < 8; ++r) {
                const float4 h4 = *(const float4*)&hch[w * 8 + r][d4 * 4];
                acc[r] = fmaf(wt.x, h4.x,
                         fmaf(wt.y, h4.y,
                         fmaf(wt.z, h4.z,
                         fmaf(wt.w, h4.w, acc[r]))));
            }
        }
#pragma unroll
        for (int i4 = 0; i4 < 4; ++i4) {
            const int dl = sl * 16 + i4 * 4;
            const float4 e4 = *(const float4*)&ek[n * D_ + kc + dl];
#pragma unroll
            for (int r = 0; r < 8; ++r) {
                const float4 h4 = *(const float4*)&hch[w * 8 + r][dl];
                accl[r] = fmaf(e4.x, h4.x,
                          fmaf(e4.y, h4.y,
                          fmaf(e4.z, h4.z,
                          fmaf(e4.w, h4.w, accl[r]))));
            }
        }
    }

    const float biv = bi[o];
#pragma unroll
    for (int r = 0; r < 8; ++r) hp[w * 8 + r][o] = acc[r] + biv;

#pragma unroll
    for (int r = 0; r < 8; ++r) {
        accl[r] += __shfl_xor(accl[r], 8);
        accl[r] += __shfl_xor(accl[r], 16);
        accl[r] += __shfl_xor(accl[r], 32);
    }
    if (sl == 0) {
#pragma unroll
        for (int r = 0; r < 8; ++r) lg[w * 8 + r][n] = accl[r] * 0.03125f;
    }
    __syncthreads();

    if (tid < RPB) {
        const int lr = tid;
        float v[NE];
        float m = -1e30f;
#pragma unroll
        for (int e = 0; e < NE; ++e) { v[e] = lg[lr][e]; m = fmaxf(m, v[e]); }
        float s = 0.f;
#pragma unroll
        for (int e = 0; e < NE; ++e) { v[e] = __expf(v[e] - m); s += v[e]; }
        const float inv = 1.f / s;
#pragma unroll
        for (int e = 0; e < NE; ++e)
            wout[(size_t)(brow + lr) * NE + e] = v[e] * inv;
    }

    if (tid < G3) {
        const int k = tid;
        for (int lr0 = 0; lr0 < RPB; lr0 += 8) {
            float pacc[8];
#pragma unroll
            for (int r = 0; r < 8; ++r) pacc[r] = 0.f;
            for (int d4 = 0; d4 < DE / 4; ++d4) {
                const float4 wv = *(const float4*)&Wih[k * DE + d4 * 4];
#pragma unroll
                for (int r = 0; r < 8; ++r) {
                    const float4 h4 = *(const float4*)&hp[lr0 + r][d4 * 4];
                    pacc[r] = fmaf(wv.x, h4.x,
                              fmaf(wv.y, h4.y,
                              fmaf(wv.z, h4.z,
                              fmaf(wv.w, h4.w, pacc[r]))));
                }
            }
#pragma unroll
            for (int r = 0; r < 8; ++r)
                Pout[(size_t)(brow + lr0 + r) * G3 + k] = pacc[r];
        }
    }
}

// ---------------- Kernel B: one-wave-per-cell GRU scan (pk_fma) ----------------
__global__ __launch_bounds__(64, 1) void scan_kernel(
    const float* __restrict__ P,   const float* __restrict__ route,
    const float* __restrict__ Whh, const float* __restrict__ bih,
    const float* __restrict__ bhh, const float* __restrict__ e0,
    float* __restrict__ out)
{
    __shared__ __align__(16) float s_l[DE];

    const int cell = blockIdx.x;
    const int b = cell >> 3;
    const int n = cell & 7;
    const int j = threadIdx.x;          // 0..63

    // W_hh rows {j, 64+j, 128+j} as f32x2 pairs (192 arch VGPRs)
    f32x2 wr2[32], wz2[32], wn2[32];
#pragma unroll
    for (int q = 0; q < 32; ++q) {
        wr2[q] = *(const f32x2*)&Whh[(size_t)j * DE + 2 * q];
        wz2[q] = *(const f32x2*)&Whh[(size_t)(64 + j) * DE + 2 * q];
        wn2[q] = *(const f32x2*)&Whh[(size_t)(128 + j) * DE + 2 * q];
    }
    const float Br   = bih[j] + bhh[j];            // r-gate combined bias
    const float Bz   = bih[64 + j] + bhh[64 + j];  // z-gate combined bias
    const float bin_ = bih[128 + j];
    const float bhn_ = bhh[128 + j];

    const size_t row0 = (size_t)b * T_;
    float s_reg = e0[n * DE + j];
    s_l[j] = s_reg;                      // same-wave ds ordering, no barrier

    const float* Pb = P + row0 * G3;
    const float* wb = route + row0 * NE + n;
    float* op = out + row0 * (size_t)(NE * DE) + n * DE + j;

    // software prefetch, depth = 2 steps
    float pr[2], pz[2], pn[2], wv[2];
#pragma unroll
    for (int i = 0; i < 2; ++i) {
        pr[i] = Pb[(size_t)i * G3 + j];
        pz[i] = Pb[(size_t)i * G3 + 64 + j];
        pn[i] = Pb[(size_t)i * G3 + 128 + j];
        wv[i] = wb[i * NE];
    }

    for (int t0 = 0; t0 < T_; t0 += 2) {
        float qr[2], qz[2], qn[2], qw[2];
        const int tb = (t0 + 2 < T_) ? (t0 + 2) : t0;   // clamp (tail reload, harmless)
#pragma unroll
        for (int i = 0; i < 2; ++i) {
            qr[i] = Pb[(size_t)(tb + i) * G3 + j];
            qz[i] = Pb[(size_t)(tb + i) * G3 + 64 + j];
            qn[i] = Pb[(size_t)(tb + i) * G3 + 128 + j];
            qw[i] = wb[(tb + i) * NE];
        }

#pragma unroll
        for (int i = 0; i < 2; ++i) {
            f32x2 aR = {0.f, 0.f}, aZ = {0.f, 0.f}, aN = {0.f, 0.f};
#pragma unroll
            for (int q = 0; q < 16; ++q) {
                const f32x4 s4 = *(const f32x4*)&s_l[q * 4];  // broadcast read
                const f32x2 slo = s4.lo;
                const f32x2 shi = s4.hi;
                pkacc(aR, wr2[2 * q],     slo);
                pkacc(aR, wr2[2 * q + 1], shi);
                pkacc(aZ, wz2[2 * q],     slo);
                pkacc(aZ, wz2[2 * q + 1], shi);
                pkacc(aN, wn2[2 * q],     slo);
                pkacc(aN, wn2[2 * q + 1], shi);
            }
            const float argR = (aR.x + aR.y) + fmaf(wv[i], pr[i], Br);
            const float argZ = (aZ.x + aZ.y) + fmaf(wv[i], pz[i], Bz);
            const float rr = __builtin_amdgcn_rcpf(1.f + __expf(-argR));
            const float zz = __builtin_amdgcn_rcpf(1.f + __expf(-argZ));
            const float u  = fmaf(wv[i], pn[i], bin_);
            const float v  = (aN.x + aN.y) + bhn_;
            const float x  = fmaf(rr, v, u);
            const float nn = fmaf(2.f, __builtin_amdgcn_rcpf(1.f + __expf(-2.f * x)), -1.f);
            const float snew = fmaf(zz, s_reg - nn, nn);   // (1-z)n + z s
            s_reg = snew;
            s_l[j] = snew;               // the single cross-lane hop
            op[(size_t)(t0 + i) * (NE * DE)] = snew;
        }

#pragma unroll
        for (int i = 0; i < 2; ++i) { pr[i] = qr[i]; pz[i] = qz[i]; pn[i] = qn[i]; wv[i] = qw[i]; }
    }
}

// ---------------- Kernel C: replicate out0 -> out1 ----------------
__global__ __launch_bounds__(256) void copy_kernel(
    const float4* __restrict__ src, float4* __restrict__ dst, int n4)
{
    int i = blockIdx.x * 256 + threadIdx.x;
    const int stride = gridDim.x * 256;
    for (; i < n4; i += stride) dst[i] = src[i];
}

extern "C" void kernel_launch(void* const* d_in, const int* in_sizes, int n_in,
                              void* d_out, int out_size, void* d_ws, size_t ws_size,
                              hipStream_t stream) {
    const float* h_seq = (const float*)d_in[0];
    const float* ek    = (const float*)d_in[1];
    const float* Wi    = (const float*)d_in[2];
    const float* bi    = (const float*)d_in[3];
    const float* Wih   = (const float*)d_in[4];
    const float* Whh   = (const float*)d_in[5];
    const float* bih   = (const float*)d_in[6];
    const float* bhh   = (const float*)d_in[7];
    const float* e0    = (const float*)d_in[8];
    float* out = (float*)d_out;

    const size_t need = (size_t)ROWS * (G3 + NE) * sizeof(float)
                      + (size_t)DE * D_ * sizeof(float);  // ~26.5 MB
    float* wbuf;
    float* Pbuf;
    float* WT4;
    if (ws_size >= need) {
        wbuf = (float*)d_ws;
    } else {
        wbuf = out + OUT1OFF;   // stash in out1; overwritten by copy at the end
    }
    Pbuf = wbuf + (size_t)ROWS * NE;
    WT4  = Pbuf + (size_t)ROWS * G3;

    wt_kernel<<<DE, 256, 0, stream>>>(Wi, WT4);
    proj_kernel<<<ROWS / RPB, 256, 0, stream>>>(h_seq, ek, WT4, bi, Wih, Pbuf, wbuf);
    scan_kernel<<<B_ * NE, 64, 0, stream>>>(Pbuf, wbuf, Whh, bih, bhh, e0, out);
    copy_kernel<<<2048, 256, 0, stream>>>((const float4*)out, (float4*)(out + OUT1OFF),
                                          OUT1OFF / 4);
}

// Round 5
// 1121.012 us; speedup vs baseline: 1.5565x; 1.0065x over previous
//
#include <hip/hip_runtime.h>
#include <hip/hip_bf16.h>

// EntityTable: B=16,T=2048,D=1024,N_E=8,D_E=64
// Phase A (parallel): hp = h@Wi^T + bi ; logits = h@ek^T/32 ; w = softmax(logits)
//                     P  = W_ih @ hp   (entity-independent input-gate projection)
// Phase B (sequential scan over T): per cell (b,n):
//   gx_k = w*P_k + b_ih_k ; gh_k = W_hh[k]·s + b_hh_k
//   r=sig(gx0+gh0) z=sig(gx1+gh1) n=tanh(gx2 + r*gh2) ; s' = (1-z)n + z s
//
// Round-5 scan: weights as 48 NAMED f32x4 SSA values (never address-taken),
// so the allocator keeps them in arch VGPRs (r2-r4 used address-taken arrays
// -> AGPR spill + v_accvgpr_read per use = the hidden ~500 cyc/step).
// One wave per cell, v_pk_fma_f32 dots, one LDS broadcast hop, no barriers.

constexpr int B_  = 16;
constexpr int T_  = 2048;
constexpr int D_  = 1024;
constexpr int NE  = 8;
constexpr int DE  = 64;
constexpr int G3  = 192;            // 3*DE
constexpr int ROWS = B_ * T_;       // 32768
constexpr int OUT1OFF = ROWS * NE * DE;  // 16777216

typedef __attribute__((ext_vector_type(2))) float f32x2;
typedef __attribute__((ext_vector_type(4))) float f32x4;

__device__ __forceinline__ void pkacc(f32x2& acc, f32x2 w, f32x2 s) {
    asm("v_pk_fma_f32 %0, %1, %2, %0" : "+v"(acc) : "v"(w), "v"(s));
}

// ---------------- Kernel T: transpose Wi -> WT4 ----------------
__global__ __launch_bounds__(256) void wt_kernel(
    const float* __restrict__ Wi, float* __restrict__ WT4)
{
    const int o  = blockIdx.x;     // 64 blocks
    const int dq = threadIdx.x;    // 256 threads
    const float4 v = *(const float4*)&Wi[o * D_ + dq * 4];
    *(float4*)&WT4[(dq * 64 + o) * 4] = v;
}

// ---------------- Kernel A: projection + routing + P ----------------
constexpr int RPB = 32;   // rows per block
constexpr int CH  = 128;  // K-chunk

__global__ __launch_bounds__(256) void proj_kernel(
    const float* __restrict__ h,   const float* __restrict__ ek,
    const float* __restrict__ WT4, const float* __restrict__ bi,
    const float* __restrict__ Wih,
    float* __restrict__ Pout, float* __restrict__ wout)
{
    __shared__ float hch[RPB][CH];   // 16 KB
    __shared__ float hp[RPB][DE];    // 8 KB
    __shared__ float lg[RPB][NE];    // 1 KB

    const int tid = threadIdx.x;
    const int brow = blockIdx.x * RPB;
    const int w = tid >> 6;          // wave 0..3
    const int o = tid & 63;          // lane = output index for hp
    const int n  = o & 7;            // entity for logit partial
    const int sl = o >> 3;           // K-slice for logit partial

    float acc[8], accl[8];
#pragma unroll
    for (int r = 0; r < 8; ++r) { acc[r] = 0.f; accl[r] = 0.f; }

    for (int kc = 0; kc < D_; kc += CH) {
        __syncthreads();
#pragma unroll
        for (int i = 0; i < 4; ++i) {
            int idx = tid + i * 256;
            int lr = idx >> 5;
            int c4 = (idx & 31) * 4;
            *(float4*)&hch[lr][c4] =
                *(const float4*)&h[(size_t)(brow + lr) * D_ + kc + c4];
        }
        __syncthreads();

        for (int d4 = 0; d4 < CH / 4; ++d4) {
            const float4 wt = *(const float4*)&WT4[((kc >> 2) + d4) * 256 + (o << 2)];
#pragma unroll
            for (int r = 0; r < 8; ++r) {
                const float4 h4 = *(const float4*)&hch[w * 8 + r][d4 * 4];
                acc[r] = fmaf(wt.x, h4.x,
                         fmaf(wt.y, h4.y,
                         fmaf(wt.z, h4.z,
                         fmaf(wt.w, h4.w, acc[r]))));
            }
        }
#pragma unroll
        for (int i4 = 0; i4 < 4; ++i4) {
            const int dl = sl * 16 + i4 * 4;
            const float4 e4 = *(const float4*)&ek[n * D_ + kc + dl];
#pragma unroll
            for (int r = 0; r < 8; ++r) {
                const float4 h4 = *(const float4*)&hch[w * 8 + r][dl];
                accl[r] = fmaf(e4.x, h4.x,
                          fmaf(e4.y, h4.y,
                          fmaf(e4.z, h4.z,
                          fmaf(e4.w, h4.w, accl[r]))));
            }
        }
    }

    const float biv = bi[o];
#pragma unroll
    for (int r = 0; r < 8; ++r) hp[w * 8 + r][o] = acc[r] + biv;

#pragma unroll
    for (int r = 0; r < 8; ++r) {
        accl[r] += __shfl_xor(accl[r], 8);
        accl[r] += __shfl_xor(accl[r], 16);
        accl[r] += __shfl_xor(accl[r], 32);
    }
    if (sl == 0) {
#pragma unroll
        for (int r = 0; r < 8; ++r) lg[w * 8 + r][n] = accl[r] * 0.03125f;
    }
    __syncthreads();

    if (tid < RPB) {
        const int lr = tid;
        float v[NE];
        float m = -1e30f;
#pragma unroll
        for (int e = 0; e < NE; ++e) { v[e] = lg[lr][e]; m = fmaxf(m, v[e]); }
        float s = 0.f;
#pragma unroll
        for (int e = 0; e < NE; ++e) { v[e] = __expf(v[e] - m); s += v[e]; }
        const float inv = 1.f / s;
#pragma unroll
        for (int e = 0; e < NE; ++e)
            wout[(size_t)(brow + lr) * NE + e] = v[e] * inv;
    }

    if (tid < G3) {
        const int k = tid;
        for (int lr0 = 0; lr0 < RPB; lr0 += 8) {
            float pacc[8];
#pragma unroll
            for (int r = 0; r < 8; ++r) pacc[r] = 0.f;
            for (int d4 = 0; d4 < DE / 4; ++d4) {
                const float4 wv = *(const float4*)&Wih[k * DE + d4 * 4];
#pragma unroll
                for (int r = 0; r < 8; ++r) {
                    const float4 h4 = *(const float4*)&hp[lr0 + r][d4 * 4];
                    pacc[r] = fmaf(wv.x, h4.x,
                              fmaf(wv.y, h4.y,
                              fmaf(wv.z, h4.z,
                              fmaf(wv.w, h4.w, pacc[r]))));
                }
            }
#pragma unroll
            for (int r = 0; r < 8; ++r)
                Pout[(size_t)(brow + lr0 + r) * G3 + k] = pacc[r];
        }
    }
}

// ---------------- Kernel B: one-wave-per-cell GRU scan (SSA weights) ----------------
// weight row q-th f32x4 for gate g at row base: Whh[(base+j)*64 + 4q]
#define DW(pre, base, q) \
    const f32x4 pre##q = *(const f32x4*)&Whh[(size_t)(base + j) * 64 + 4 * q];
#define DW16(pre, base) \
    DW(pre, base, 0)  DW(pre, base, 1)  DW(pre, base, 2)  DW(pre, base, 3)  \
    DW(pre, base, 4)  DW(pre, base, 5)  DW(pre, base, 6)  DW(pre, base, 7)  \
    DW(pre, base, 8)  DW(pre, base, 9)  DW(pre, base, 10) DW(pre, base, 11) \
    DW(pre, base, 12) DW(pre, base, 13) DW(pre, base, 14) DW(pre, base, 15)

#define MACQ(q) { \
    const f32x4 s4 = *(const f32x4*)&s_l[4 * (q)]; \
    const f32x2 lo = s4.lo, hi = s4.hi; \
    pkacc(aR, wr##q.lo, lo); pkacc(aR, wr##q.hi, hi); \
    pkacc(aZ, wz##q.lo, lo); pkacc(aZ, wz##q.hi, hi); \
    pkacc(aN, wn##q.lo, lo); pkacc(aN, wn##q.hi, hi); }
#define MAC16() \
    MACQ(0)  MACQ(1)  MACQ(2)  MACQ(3)  MACQ(4)  MACQ(5)  MACQ(6)  MACQ(7) \
    MACQ(8)  MACQ(9)  MACQ(10) MACQ(11) MACQ(12) MACQ(13) MACQ(14) MACQ(15)

__global__ __launch_bounds__(64, 1) void scan_kernel(
    const float* __restrict__ P,   const float* __restrict__ route,
    const float* __restrict__ Whh, const float* __restrict__ bih,
    const float* __restrict__ bhh, const float* __restrict__ e0,
    float* __restrict__ out)
{
    __shared__ __align__(16) float s_l[DE];

    // XCD co-location: all 8 entity-cells of a batch b land on the same XCD
    // (dispatch round-robins blockIdx % 8) so they share the P rows in L2.
    const int g   = blockIdx.x;          // 0..127
    const int xcd = g & 7;
    const int ii  = g >> 3;              // 0..15
    const int b   = xcd + 8 * (ii & 1);
    const int n   = ii >> 1;
    const int j   = threadIdx.x;         // 0..63

    // 48 named SSA f32x4 weights (192 floats -> arch VGPRs, no AGPR spill)
    DW16(wr, 0)
    DW16(wz, 64)
    DW16(wn, 128)

    const float Br   = bih[j] + bhh[j];            // r-gate combined bias
    const float Bz   = bih[64 + j] + bhh[64 + j];  // z-gate combined bias
    const float bin_ = bih[128 + j];
    const float bhn_ = bhh[128 + j];

    const size_t row0 = (size_t)b * T_;
    float s_reg = e0[n * DE + j];
    s_l[j] = s_reg;                      // same-wave ds ordering, no barrier

    const float* Pb = P + row0 * G3;
    const float* wb = route + row0 * NE + n;
    float* op = out + row0 * (size_t)(NE * DE) + n * DE + j;

    // software prefetch, depth = 2 steps
    float pr0 = Pb[j],            pr1 = Pb[G3 + j];
    float pz0 = Pb[64 + j],       pz1 = Pb[G3 + 64 + j];
    float pn0 = Pb[128 + j],      pn1 = Pb[G3 + 128 + j];
    float wv0 = wb[0],            wv1 = wb[NE];

    for (int t0 = 0; t0 < T_; t0 += 2) {
        const int tb = (t0 + 2 < T_) ? (t0 + 2) : t0;   // tail clamp (reload, harmless)
        const float qr0 = Pb[(size_t)(tb) * G3 + j];
        const float qz0 = Pb[(size_t)(tb) * G3 + 64 + j];
        const float qn0 = Pb[(size_t)(tb) * G3 + 128 + j];
        const float qw0 = wb[tb * NE];
        const float qr1 = Pb[(size_t)(tb + 1) * G3 + j];
        const float qz1 = Pb[(size_t)(tb + 1) * G3 + 64 + j];
        const float qn1 = Pb[(size_t)(tb + 1) * G3 + 128 + j];
        const float qw1 = wb[(tb + 1) * NE];

#pragma unroll
        for (int i = 0; i < 2; ++i) {
            const float pri = i ? pr1 : pr0;
            const float pzi = i ? pz1 : pz0;
            const float pni = i ? pn1 : pn0;
            const float wvi = i ? wv1 : wv0;

            f32x2 aR = {0.f, 0.f}, aZ = {0.f, 0.f}, aN = {0.f, 0.f};
            MAC16()

            const float argR = (aR.x + aR.y) + fmaf(wvi, pri, Br);
            const float argZ = (aZ.x + aZ.y) + fmaf(wvi, pzi, Bz);
            const float rr = __builtin_amdgcn_rcpf(1.f + __expf(-argR));
            const float zz = __builtin_amdgcn_rcpf(1.f + __expf(-argZ));
            const float u  = fmaf(wvi, pni, bin_);
            const float v  = (aN.x + aN.y) + bhn_;
            const float x  = fmaf(rr, v, u);
            const float nn = fmaf(2.f, __builtin_amdgcn_rcpf(1.f + __expf(-2.f * x)), -1.f);
            const float snew = fmaf(zz, s_reg - nn, nn);   // (1-z)n + z s
            s_reg = snew;
            s_l[j] = snew;               // the single cross-lane hop
            op[(size_t)(t0 + i) * (NE * DE)] = snew;
        }

        pr0 = qr0; pz0 = qz0; pn0 = qn0; wv0 = qw0;
        pr1 = qr1; pz1 = qz1; pn1 = qn1; wv1 = qw1;
    }
}

// ---------------- Kernel C: replicate out0 -> out1 ----------------
__global__ __launch_bounds__(256) void copy_kernel(
    const float4* __restrict__ src, float4* __restrict__ dst, int n4)
{
    int i = blockIdx.x * 256 + threadIdx.x;
    const int stride = gridDim.x * 256;
    for (; i < n4; i += stride) dst[i] = src[i];
}

extern "C" void kernel_launch(void* const* d_in, const int* in_sizes, int n_in,
                              void* d_out, int out_size, void* d_ws, size_t ws_size,
                              hipStream_t stream) {
    const float* h_seq = (const float*)d_in[0];
    const float* ek    = (const float*)d_in[1];
    const float* Wi    = (const float*)d_in[2];
    const float* bi    = (const float*)d_in[3];
    const float* Wih   = (const float*)d_in[4];
    const float* Whh   = (const float*)d_in[5];
    const float* bih   = (const float*)d_in[6];
    const float* bhh   = (const float*)d_in[7];
    const float* e0    = (const float*)d_in[8];
    float* out = (float*)d_out;

    const size_t need = (size_t)ROWS * (G3 + NE) * sizeof(float)
                      + (size_t)DE * D_ * sizeof(float);  // ~26.5 MB
    float* wbuf;
    if (ws_size >= need) {
        wbuf = (float*)d_ws;
    } else {
        wbuf = out + OUT1OFF;   // stash in out1; overwritten by copy at the end
    }
    float* Pbuf = wbuf + (size_t)ROWS * NE;
    float* WT4  = Pbuf + (size_t)ROWS * G3;

    wt_kernel<<<DE, 256, 0, stream>>>(Wi, WT4);
    proj_kernel<<<ROWS / RPB, 256, 0, stream>>>(h_seq, ek, WT4, bi, Wih, Pbuf, wbuf);
    scan_kernel<<<B_ * NE, 64, 0, stream>>>(Pbuf, wbuf, Whh, bih, bhh, e0, out);
    copy_kernel<<<2048, 256, 0, stream>>>((const float4*)out, (float4*)(out + OUT1OFF),
                                          OUT1OFF / 4);
}